// Round 2
// baseline (19.986 us; speedup 1.0000x reference)
//
#include <hip/hip_runtime.h>

// MemristorConv1d: (B=4, F=512, T=1000), K=31, 3 bit-planes.
// out[b,f,t] = ( sum_p BW[p] * ADC( sum_k d[b,f,t+k-15] * wdiff[p,f,k] ) ) * 0.02 + bias[f]
// d(v)  = v * (Phrs(v^2) - Plrs(v^2)),  v = DAC(in * 0.25),  d(0) == 0 so zero-padding raw input is exact.

#define KW 31
#define TT 1000
#define FF 512
#define NP 3
#define RPT 8              // outputs per thread
#define THR 128            // threads per block; 125 active (125*8 = 1000)
#define NCHUNK 10          // float4 chunks per thread window (40 floats)

__device__ __forceinline__ float adc_q(float c) {
    // round(c*5000/2^-8)*2^-8, clip +-16; *1280000 is exact-equivalent scaling.
    return fminf(fmaxf(rintf(c * 1280000.0f) * (1.0f / 256.0f), -16.0f), 16.0f);
}

__global__ void wdiff_kernel(const float* __restrict__ r_pos,
                             const float* __restrict__ r_neg,
                             float* __restrict__ wd) {
    const int i = blockIdx.x * 256 + threadIdx.x;     // over NP*FF*KW = 47616
    if (i < NP * FF * KW) {
        const int k  = i % KW;
        const int pf = i / KW;
        const int p  = pf / FF;
        const int f  = pf - p * FF;
        // reorder to [f][p][k] so each block's 93 weights are contiguous -> s_load_dwordx16
        wd[((size_t)f * NP + p) * KW + k] = r_pos[i] - r_neg[i];
    }
}

template <bool USE_WS>
__global__ __launch_bounds__(THR) void memristor_conv1d_kernel(
    const float* __restrict__ inputs,   // (B,F,T)
    const float* __restrict__ wdiff,    // (F,NP,K) if USE_WS
    const float* __restrict__ r_pos,    // (NP,F,K) fallback
    const float* __restrict__ r_neg,    // (NP,F,K) fallback
    const float* __restrict__ bias,     // (F)
    float* __restrict__ out)            // (B,F,T)
{
    const int bf = blockIdx.x;          // b*F + f
    const int f  = bf & (FF - 1);
    const int t  = threadIdx.x;
    if (t >= TT / RPT) return;          // threads 125..127 idle

    const float* __restrict__ row = inputs + (size_t)bf * TT;

    // ---- load 40-float window (chunk-aligned float4s), zero-pad out of range ----
    float d[NCHUNK * 4];
    const int c0 = 2 * t - 4;           // first chunk; window floats cover [8t-16, 8t+23]
    #pragma unroll
    for (int c = 0; c < NCHUNK; ++c) {
        const int cc = c0 + c;
        float4 v = make_float4(0.f, 0.f, 0.f, 0.f);
        if (cc >= 0 && cc < TT / 4)
            v = reinterpret_cast<const float4*>(row)[cc];
        d[4 * c + 0] = v.x; d[4 * c + 1] = v.y; d[4 * c + 2] = v.z; d[4 * c + 3] = v.w;
    }

    // ---- DAC + fused polynomial, in place (indices 1..38 are the ones used) ----
    #pragma unroll
    for (int i = 1; i <= 38; ++i) {
        float v = fminf(fmaxf(d[i] * 0.25f, -1.0f), 1.0f);
        v = rintf(v * 127.0f) * (0.6f / 127.0f);
        const float v2 = v * v;
        // Phrs - Plrs with constants folded: 2 FMA + 1 mul
        d[i] = v * fmaf(v2, fmaf(v2, (1e-09f - 2e-07f), (5e-08f - 4e-06f)),
                        (2e-06f - 3e-04f));
    }

    // ---- 31-tap FIR, 3 bit-planes, weights via wave-uniform scalar loads ----
    float acc[NP][RPT] = {};
    const float* __restrict__ wf;
    if (USE_WS) wf = wdiff + (size_t)f * (NP * KW);
    #pragma unroll
    for (int k = 0; k < KW; ++k) {
        float w0, w1, w2;
        if (USE_WS) {
            w0 = wf[0 * KW + k]; w1 = wf[1 * KW + k]; w2 = wf[2 * KW + k];
        } else {
            const size_t o0 = ((size_t)0 * FF + f) * KW + k;
            const size_t o1 = ((size_t)1 * FF + f) * KW + k;
            const size_t o2 = ((size_t)2 * FF + f) * KW + k;
            w0 = r_pos[o0] - r_neg[o0];
            w1 = r_pos[o1] - r_neg[o1];
            w2 = r_pos[o2] - r_neg[o2];
        }
        #pragma unroll
        for (int r = 0; r < RPT; ++r) {
            const float dv = d[r + 1 + k];
            acc[0][r] = fmaf(dv, w0, acc[0][r]);
            acc[1][r] = fmaf(dv, w1, acc[1][r]);
            acc[2][r] = fmaf(dv, w2, acc[2][r]);
        }
    }

    // ---- ADC, bit-weight combine, bias; store 8 outputs as two float4 ----
    const float bv = bias[f];
    float o[RPT];
    #pragma unroll
    for (int r = 0; r < RPT; ++r) {
        const float a0 = adc_q(acc[0][r]);
        const float a1 = adc_q(acc[1][r]);
        const float a2 = adc_q(acc[2][r]);
        o[r] = fmaf(a0 * 4.0f + a1 * 2.0f + a2, 0.02f, bv);
    }
    float* __restrict__ orow = out + (size_t)bf * TT + RPT * t;
    reinterpret_cast<float4*>(orow)[0] = make_float4(o[0], o[1], o[2], o[3]);
    reinterpret_cast<float4*>(orow)[1] = make_float4(o[4], o[5], o[6], o[7]);
}

extern "C" void kernel_launch(void* const* d_in, const int* in_sizes, int n_in,
                              void* d_out, int out_size, void* d_ws, size_t ws_size,
                              hipStream_t stream) {
    const float* inputs = (const float*)d_in[0];   // (4,512,1000)
    const float* r_pos  = (const float*)d_in[1];   // (3,512,31)
    const float* r_neg  = (const float*)d_in[2];   // (3,512,31)
    const float* bias   = (const float*)d_in[3];   // (512)
    float* out = (float*)d_out;                    // (4,512,1000)

    const int B = in_sizes[0] / (FF * TT);         // 4
    const dim3 grid(B * FF);
    const dim3 block(THR);

    const size_t wd_bytes = (size_t)NP * FF * KW * sizeof(float);
    if (ws_size >= wd_bytes) {
        float* wd = (float*)d_ws;
        wdiff_kernel<<<dim3((NP * FF * KW + 255) / 256), dim3(256), 0, stream>>>(
            r_pos, r_neg, wd);
        memristor_conv1d_kernel<true><<<grid, block, 0, stream>>>(
            inputs, wd, r_pos, r_neg, bias, out);
    } else {
        memristor_conv1d_kernel<false><<<grid, block, 0, stream>>>(
            inputs, nullptr, r_pos, r_neg, bias, out);
    }
}

// Round 3
// 15.761 us; speedup vs baseline: 1.2680x; 1.2680x over previous
//
#include <hip/hip_runtime.h>

// MemristorConv1d: (B=4, F=512, T=1000), K=31, 3 bit-planes. Single fused kernel.
// out[b,f,t] = ( sum_p BW[p] * ADC( sum_k d[b,f,t+k-15] * (r_pos-r_neg)[p,f,k] ) ) * 0.02 + bias[f]
// d(v) = v*(Phrs(v2)-Plrs(v2)), v = DAC(in*0.25); d(0)==0 so zero padding is exact.

#define KW 31
#define PADW 15
#define TT 1000
#define FF 512
#define NP 3
#define RPT 8              // outputs per thread
#define THR 128            // 125 active in FIR phase
#define ACTIVE (TT / RPT)  // 125
#define DL 1032            // padded d[] length (>= 1030, multiple of 4)

__device__ __forceinline__ float rdlane_f(float v, int lane) {
    // compile-time lane index -> v_readlane_b32 (SGPR broadcast, exec-independent)
    return __int_as_float(__builtin_amdgcn_readlane(__float_as_int(v), lane));
}

__device__ __forceinline__ float adc_q(float c) {
    // round(c*5000/2^-8)*2^-8, clip +-16 (x1280000 is an exact-equivalent scale)
    return fminf(fmaxf(rintf(c * 1280000.0f) * (1.0f / 256.0f), -16.0f), 16.0f);
}

__global__ __launch_bounds__(THR) void memristor_kernel(
    const float* __restrict__ inputs,   // (B,F,T)
    const float* __restrict__ r_pos,    // (NP,F,K)
    const float* __restrict__ r_neg,    // (NP,F,K)
    const float* __restrict__ bias,     // (F)
    float* __restrict__ out)            // (B,F,T)
{
    const int bf  = blockIdx.x;         // b*F + f
    const int f   = bf & (FF - 1);
    const int tid = threadIdx.x;

    __shared__ float d_lds[DL];

    // ---- stage the 93 weight-diffs into lanes: lane l holds wd[l], wd[64+l] ----
    const int lane = tid & 63;
    float w_lo = 0.0f, w_hi = 0.0f;
    if (lane < NP * KW) {
        const int p = lane / KW, k = lane - p * KW;
        const size_t o = ((size_t)p * FF + f) * KW + k;
        w_lo = r_pos[o] - r_neg[o];
    }
    if (lane + 64 < NP * KW) {
        const int l2 = lane + 64;
        const int p = l2 / KW, k = l2 - p * KW;
        const size_t o = ((size_t)p * FF + f) * KW + k;
        w_hi = r_pos[o] - r_neg[o];
    }

    // ---- phase 1: DAC + fused polynomial ONCE per element, into LDS ----
    const float* __restrict__ row = inputs + (size_t)bf * TT;
    for (int i = tid; i < DL; i += THR) {
        float dv = 0.0f;
        const int ti = i - PADW;
        if (ti >= 0 && ti < TT) {
            float v = fminf(fmaxf(row[ti] * 0.25f, -1.0f), 1.0f);
            v = rintf(v * 127.0f) * (0.6f / 127.0f);     // rintf == jnp.round (half-even)
            const float v2 = v * v;
            dv = v * fmaf(v2, fmaf(v2, (1e-09f - 2e-07f), (5e-08f - 4e-06f)),
                          (2e-06f - 3e-04f));
        }
        d_lds[i] = dv;
    }
    __syncthreads();

    if (tid >= ACTIVE) return;

    // ---- window into registers: 10 x ds_read_b128, conflict-free ----
    const int t8 = tid * RPT;
    float win[40];
    {
        const float4* dl4 = reinterpret_cast<const float4*>(&d_lds[t8]);
        #pragma unroll
        for (int c = 0; c < 10; ++c) {
            const float4 v = dl4[c];
            win[4 * c + 0] = v.x; win[4 * c + 1] = v.y;
            win[4 * c + 2] = v.z; win[4 * c + 3] = v.w;
        }
    }

    // ---- FIR: 31 taps x 3 planes x 8 outputs; weights via readlane broadcast ----
    float acc[NP][RPT] = {};
    #pragma unroll
    for (int k = 0; k < KW; ++k) {
        #pragma unroll
        for (int p = 0; p < NP; ++p) {
            const int flat = p * KW + k;                     // compile-time
            const float w = rdlane_f(flat < 64 ? w_lo : w_hi, flat & 63);
            #pragma unroll
            for (int r = 0; r < RPT; ++r)
                acc[p][r] = fmaf(win[r + k], w, acc[p][r]);
        }
    }

    // ---- ADC, bit-weight combine, bias; 2 x float4 store ----
    const float bv = bias[f];
    float o[RPT];
    #pragma unroll
    for (int r = 0; r < RPT; ++r) {
        o[r] = fmaf(adc_q(acc[0][r]) * 4.0f + adc_q(acc[1][r]) * 2.0f + adc_q(acc[2][r]),
                    0.02f, bv);
    }
    float* __restrict__ orow = out + (size_t)bf * TT + t8;
    reinterpret_cast<float4*>(orow)[0] = make_float4(o[0], o[1], o[2], o[3]);
    reinterpret_cast<float4*>(orow)[1] = make_float4(o[4], o[5], o[6], o[7]);
}

extern "C" void kernel_launch(void* const* d_in, const int* in_sizes, int n_in,
                              void* d_out, int out_size, void* d_ws, size_t ws_size,
                              hipStream_t stream) {
    const float* inputs = (const float*)d_in[0];   // (4,512,1000)
    const float* r_pos  = (const float*)d_in[1];   // (3,512,31)
    const float* r_neg  = (const float*)d_in[2];   // (3,512,31)
    const float* bias   = (const float*)d_in[3];   // (512)
    float* out = (float*)d_out;                    // (4,512,1000)

    const int B = in_sizes[0] / (FF * TT);         // 4
    memristor_kernel<<<dim3(B * FF), dim3(THR), 0, stream>>>(
        inputs, r_pos, r_neg, bias, out);
}

// Round 5
// 15.705 us; speedup vs baseline: 1.2725x; 1.0036x over previous
//
#include <hip/hip_runtime.h>

// MemristorConv1d: (B=4, F=512, T=1000), K=31, 3 bit-planes.
// out[b,f,t] = ( sum_p BW[p] * ADC( sum_k d[b,f,t+k-15] * (r_pos[p,f,k]-r_neg[p,f,k]) ) ) * 0.02 + bias[f]
// d(v)  = v * (Phrs(v^2) - Plrs(v^2)),  v = DAC(in * 0.25)
// R0 kernel verbatim: passed at 15.21 us with absmax 1.95e-3 (32x margin).

#define KW 31
#define PADW 15
#define TT 1000
#define FF 512
#define NP 3
#define BLOCK 256

__global__ __launch_bounds__(BLOCK) void memristor_conv1d_kernel(
    const float* __restrict__ inputs,   // (B,F,T)
    const float* __restrict__ r_pos,    // (NP,F,K)
    const float* __restrict__ r_neg,    // (NP,F,K)
    const float* __restrict__ bias,     // (F)
    float* __restrict__ out)            // (B,F,T)
{
    const int bf  = blockIdx.x;         // b*F + f
    const int f   = bf & (FF - 1);
    const int tid = threadIdx.x;

    __shared__ float d_lds[TT + 2 * PADW];   // 1030 floats
    __shared__ float w_lds[NP][KW];          // 93 floats

    // Stage weights (r_pos - r_neg) for this feature.
    if (tid < NP * KW) {
        const int p = tid / KW;
        const int k = tid - p * KW;
        const size_t off = ((size_t)p * FF + f) * KW + k;
        w_lds[p][k] = r_pos[off] - r_neg[off];
    }

    // Stage input row -> DAC -> polynomial "diff" factor, with zero padding.
    const float* in_row = inputs + (size_t)bf * TT;
    for (int t = tid; t < TT + 2 * PADW; t += BLOCK) {
        float dv = 0.0f;
        const int ti = t - PADW;
        if (ti >= 0 && ti < TT) {
            // DAC: clip, quantize to 127 levels, scale to +-0.6 V
            float x = in_row[ti] * 0.25f;
            float v = fminf(fmaxf(x, -1.0f), 1.0f);
            v = rintf(v * 127.0f) / 127.0f * 0.6f;   // rintf == round-half-even == jnp.round
            // diff = v * (Phrs(v2) - Plrs(v2))
            const float v2 = v * v;
            const float ph = 2e-06f + v2 * (5e-08f + v2 * 1e-09f);
            const float pl = 3e-04f + v2 * (4e-06f + v2 * 2e-07f);
            dv = v * (ph - pl);
        }
        d_lds[t] = dv;
    }
    __syncthreads();

    const float bv = bias[f];
    float* out_row = out + (size_t)bf * TT;

    for (int t = tid; t < TT; t += BLOCK) {
        float c0 = 0.0f, c1 = 0.0f, c2 = 0.0f;
        #pragma unroll
        for (int k = 0; k < KW; ++k) {
            const float dv = d_lds[t + k];
            c0 = fmaf(dv, w_lds[0][k], c0);
            c1 = fmaf(dv, w_lds[1][k], c1);
            c2 = fmaf(dv, w_lds[2][k], c2);
        }
        // ADC: round(i*5000/2^-8)*2^-8, clip to +-16.
        // c * (5000*256) rounds identically to (c*5000)*256 (exact pow2 scale).
        float a0 = fminf(fmaxf(rintf(c0 * 1280000.0f) * (1.0f / 256.0f), -16.0f), 16.0f);
        float a1 = fminf(fmaxf(rintf(c1 * 1280000.0f) * (1.0f / 256.0f), -16.0f), 16.0f);
        float a2 = fminf(fmaxf(rintf(c2 * 1280000.0f) * (1.0f / 256.0f), -16.0f), 16.0f);
        out_row[t] = (a0 * 4.0f + a1 * 2.0f + a2) * 0.02f + bv;
    }
}

extern "C" void kernel_launch(void* const* d_in, const int* in_sizes, int n_in,
                              void* d_out, int out_size, void* d_ws, size_t ws_size,
                              hipStream_t stream) {
    const float* inputs = (const float*)d_in[0];   // (4,512,1000)
    const float* r_pos  = (const float*)d_in[1];   // (3,512,31)
    const float* r_neg  = (const float*)d_in[2];   // (3,512,31)
    const float* bias   = (const float*)d_in[3];   // (512)
    float* out = (float*)d_out;                    // (4,512,1000)

    const int B = in_sizes[0] / (FF * TT);         // 4
    dim3 grid(B * FF);
    dim3 block(BLOCK);
    memristor_conv1d_kernel<<<grid, block, 0, stream>>>(inputs, r_pos, r_neg, bias, out);
}